// Round 3
// baseline (137.105 us; speedup 1.0000x reference)
//
#include <hip/hip_runtime.h>
#include <math.h>

#define HID 64

__device__ __forceinline__ float fast_tanh(float x) {
    // tanh(x) = 1 - 2/(exp(2x)+1); exp overflow -> inf -> rcp -> 0 -> 1 (correct)
    float e = __expf(2.0f * x);
    return 1.0f - 2.0f * __builtin_amdgcn_rcpf(e + 1.0f);
}

// ---- E_des pre-kernel: one wave, computed once into d_ws[0] ----
__global__ void edes_kernel(const float* __restrict__ W1, const float* __restrict__ b1,
                            const float* __restrict__ W2, const float* __restrict__ b2,
                            const float* __restrict__ W3, const float* __restrict__ b3,
                            const float* __restrict__ x0, float* __restrict__ out) {
    int j = threadIdx.x;  // 0..63
    float q1 = x0[0], q2 = x0[1], p1 = x0[2], p2 = x0[3];

    // lane j owns hidden unit j end-to-end
    float h1j = fast_tanh(fmaf(q1, W1[j], fmaf(q2, W1[HID + j], b1[j])));

    // z2[j] = sum_i h1[i] * W2[i][j]; broadcast h1[i] via shfl
    float z = b2[j];
#pragma unroll 1
    for (int i = 0; i < HID; i++) {
        float hi = __shfl(h1j, i, 64);
        z = fmaf(hi, W2[i * HID + j], z);
    }
    float h2 = fast_tanh(z);
    float v = h2 * W3[j];
#pragma unroll
    for (int off = 32; off; off >>= 1) v += __shfl_xor(v, off, 64);

    if (j == 0) {
        float V = v + b3[0];
        float s, c;
        __sincosf(q2, &s, &c);
        float DEN = 2.0f - c * c;
        float rDEN = __builtin_amdgcn_rcpf(DEN);
        float quad = (p1 * p1 - 2.0f * (c + 1.0f) * p1 * p2 + (2.0f * c + 3.0f) * p2 * p2) * rDEN;
        float kin = 0.5f * quad;
        float s1, c1;
        __sincosf(q1, &s1, &c1);
        float c12 = c1 * c - s1 * s;
        float dq = 1.57079632679489662f - q2;
        float pot = -9.81f * (c12 + 2.0f * c1) + 0.5f * dq * dq;
        out[0] = pot + kin + V;
    }
}

// ---- Main kernel: one thread per batch element; i-loops are REAL loops ----
__global__ __launch_bounds__(256, 2) void pend_kernel(
    const float4* __restrict__ x,
    const float* __restrict__ W1, const float* __restrict__ b1,
    const float* __restrict__ W2, const float* __restrict__ b2,
    const float* __restrict__ W3, const float* __restrict__ b3,
    const float* __restrict__ Tp, const float* __restrict__ edes_p,
    float4* __restrict__ out, int n)
{
    int t = blockIdx.x * blockDim.x + threadIdx.x;
    if (t >= n) return;

    float4 xv = x[t];
    float q1 = xv.x, q2 = xv.y, p1 = xv.z, p2 = xv.w;
    float E_des = edes_p[0];
    float Tabs = fabsf(Tp[0]);

    // ---- layer 2 forward, layer 1 fused (h1[i] recomputed per i) ----
    float acc[HID];
#pragma unroll
    for (int j = 0; j < HID; j++) acc[j] = b2[j];

#pragma unroll 1
    for (int i = 0; i < HID; i++) {
        float h = fast_tanh(fmaf(q1, W1[i], fmaf(q2, W1[HID + i], b1[i])));
        const float* w2row = W2 + i * HID;   // wave-uniform address -> s_load rows
#pragma unroll
        for (int j = 0; j < HID; j++)
            acc[j] = fmaf(h, w2row[j], acc[j]);
    }

    // ---- V and g2 (reuse acc as g2[j] = W3[j]*(1-h2^2)) ----
    float vp0 = 0.f, vp1 = 0.f, vp2 = 0.f, vp3 = 0.f;
#pragma unroll
    for (int j = 0; j < HID; j += 4) {
        float a0 = fast_tanh(acc[j + 0]);
        float a1 = fast_tanh(acc[j + 1]);
        float a2 = fast_tanh(acc[j + 2]);
        float a3 = fast_tanh(acc[j + 3]);
        vp0 = fmaf(a0, W3[j + 0], vp0);
        vp1 = fmaf(a1, W3[j + 1], vp1);
        vp2 = fmaf(a2, W3[j + 2], vp2);
        vp3 = fmaf(a3, W3[j + 3], vp3);
        acc[j + 0] = W3[j + 0] * (1.0f - a0 * a0);
        acc[j + 1] = W3[j + 1] * (1.0f - a1 * a1);
        acc[j + 2] = W3[j + 2] * (1.0f - a2 * a2);
        acc[j + 3] = W3[j + 3] * (1.0f - a3 * a3);
    }
    float V = b3[0] + ((vp0 + vp1) + (vp2 + vp3));

    // ---- backward: gi = (1-h1[i]^2) * sum_j W2[i][j]*g2[j]; dVdq = W1^T g1 ----
    float dVq1 = 0.0f, dVq2 = 0.0f;
#pragma unroll 1
    for (int i = 0; i < HID; i++) {
        float h = fast_tanh(fmaf(q1, W1[i], fmaf(q2, W1[HID + i], b1[i])));
        const float* w2row = W2 + i * HID;
        float s0 = 0.f, s1 = 0.f, s2 = 0.f, s3 = 0.f;
#pragma unroll
        for (int j = 0; j < HID; j += 4) {
            s0 = fmaf(w2row[j + 0], acc[j + 0], s0);
            s1 = fmaf(w2row[j + 1], acc[j + 1], s1);
            s2 = fmaf(w2row[j + 2], acc[j + 2], s2);
            s3 = fmaf(w2row[j + 3], acc[j + 3], s3);
        }
        float gi = (1.0f - h * h) * ((s0 + s1) + (s2 + s3));
        dVq1 = fmaf(W1[i],       gi, dVq1);
        dVq2 = fmaf(W1[HID + i], gi, dVq2);
    }

    // ---- physics (L1=L2=M1=M2=1, G=9.81, K1=0.5, A_E=1, B_DAMP=0) ----
    float s2q, c2q, s1q, c1q;
    __sincosf(q2, &s2q, &c2q);
    __sincosf(q1, &s1q, &c1q);
    float s12 = s1q * c2q + c1q * s2q;
    float c12 = c1q * c2q - s1q * s2q;

    float c = c2q, s = s2q;
    float DEN = 2.0f - c * c;            // == 1 + s^2
    float rDEN = __builtin_amdgcn_rcpf(DEN);
    float cp1 = c + 1.0f;

    float quad = (p1 * p1 - 2.0f * cp1 * p1 * p2 + (2.0f * c + 3.0f) * p2 * p2) * rDEN;
    float kin = 0.5f * quad;
    float dqa = 1.57079632679489662f - q2;
    float pot = -9.81f * (c12 + 2.0f * c1q) + 0.5f * dqa * dqa;
    float E = pot + kin + V;

    float fac = (quad > 0.0f) ? __builtin_amdgcn_rsqf(quad) : 1.0f;
    float coef = E_des - E;
    float u1 = -dVq1 + coef * p1 * fac;
    float u2 = -dVq2 + coef * p2 * fac;

    float dq1dt = (p1 - cp1 * p2) * rDEN;
    float dq2dt = ((2.0f * c + 3.0f) * p2 - cp1 * p1) * rDEN;
    float dp1dt = -9.81f * (s12 + 2.0f * s1q) + u1;

    float inner = -p2 * p2 * s * cp1 * (c + 2.0f)
                + p1 * p2 * s * (fmaf(c, c, fmaf(2.0f, c, 2.0f)))
                - c * p1 * p1 * s
                + DEN * DEN * (fmaf(9.81f, s12, -0.5f * (3.14159265358979324f - 2.0f * q2)));
    float dp2dt = -(inner * rDEN * rDEN) + u2;

    float4 o;
    o.x = Tabs * dq1dt;
    o.y = Tabs * dq2dt;
    o.z = Tabs * dp1dt;
    o.w = Tabs * dp2dt;
    out[t] = o;
}

extern "C" void kernel_launch(void* const* d_in, const int* in_sizes, int n_in,
                              void* d_out, int out_size, void* d_ws, size_t ws_size,
                              hipStream_t stream) {
    const float* x  = (const float*)d_in[0];
    // d_in[1] = t (unused)
    const float* W1 = (const float*)d_in[2];
    const float* b1 = (const float*)d_in[3];
    const float* W2 = (const float*)d_in[4];
    const float* b2 = (const float*)d_in[5];
    const float* W3 = (const float*)d_in[6];
    const float* b3 = (const float*)d_in[7];
    const float* Tp = (const float*)d_in[8];
    const float* x0 = (const float*)d_in[9];

    float* edes = (float*)d_ws;
    edes_kernel<<<1, 64, 0, stream>>>(W1, b1, W2, b2, W3, b3, x0, edes);

    int n = in_sizes[0] / 4;  // 500000
    int blocks = (n + 255) / 256;
    pend_kernel<<<blocks, 256, 0, stream>>>((const float4*)x, W1, b1, W2, b2, W3, b3,
                                            Tp, edes, (float4*)d_out, n);
}

// Round 4
// 85.764 us; speedup vs baseline: 1.5986x; 1.5986x over previous
//
#include <hip/hip_runtime.h>
#include <math.h>

#define HID 64

typedef __attribute__((ext_vector_type(4))) float f32x4;
typedef __attribute__((ext_vector_type(8))) __bf16 bf16x8;

__device__ __forceinline__ float fast_tanh(float x) {
    // tanh(x) = 1 - 2/(exp(2x)+1); exp overflow -> inf -> rcp -> 0 -> 1 (correct)
    float e = __expf(2.0f * x);
    return 1.0f - 2.0f * __builtin_amdgcn_rcpf(e + 1.0f);
}

// ---- prep: bf16 weight tables (W2, W2^T) + E_des, all into d_ws ----
__global__ void prep_kernel(const float* __restrict__ W1, const float* __restrict__ b1,
                            const float* __restrict__ W2, const float* __restrict__ b2,
                            const float* __restrict__ W3, const float* __restrict__ b3,
                            const float* __restrict__ x0, float* __restrict__ edes_out,
                            __bf16* __restrict__ W2bf, __bf16* __restrict__ W2Tbf) {
    int tid = threadIdx.x;  // 256 threads
    for (int idx = tid; idx < HID * HID; idx += 256) {
        W2bf[idx] = (__bf16)W2[idx];
        int r = idx >> 6, c = idx & 63;
        W2Tbf[idx] = (__bf16)W2[c * HID + r];
    }
    if (tid < 64) {
        int j = tid;
        float q1 = x0[0], q2 = x0[1], p1 = x0[2], p2 = x0[3];
        float h1j = fast_tanh(fmaf(q1, W1[j], fmaf(q2, W1[HID + j], b1[j])));
        float z = b2[j];
#pragma unroll 1
        for (int i = 0; i < HID; i++) {
            float hi = __shfl(h1j, i, 64);
            z = fmaf(hi, W2[i * HID + j], z);
        }
        float h2 = fast_tanh(z);
        float v = h2 * W3[j];
#pragma unroll
        for (int off = 32; off; off >>= 1) v += __shfl_xor(v, off, 64);
        if (j == 0) {
            float V = v + b3[0];
            float s, c;
            __sincosf(q2, &s, &c);
            float DEN = 2.0f - c * c;
            float rDEN = __builtin_amdgcn_rcpf(DEN);
            float quad = (p1 * p1 - 2.0f * (c + 1.0f) * p1 * p2 + (2.0f * c + 3.0f) * p2 * p2) * rDEN;
            float kin = 0.5f * quad;
            float s1, c1;
            __sincosf(q1, &s1, &c1);
            float c12 = c1 * c - s1 * s;
            float dq = 1.57079632679489662f - q2;
            float pot = -9.81f * (c12 + 2.0f * c1) + 0.5f * dq * dq;
            edes_out[0] = pot + kin + V;
        }
    }
}

// ---- main: 16 batch rows per wave, MFMA for both 64x64 GEMMs ----
__global__ __launch_bounds__(256, 4) void pend_kernel(
    const float4* __restrict__ x,
    const float* __restrict__ W1, const float* __restrict__ b1,
    const __bf16* __restrict__ W2bf, const __bf16* __restrict__ W2Tbf,
    const float* __restrict__ b2,
    const float* __restrict__ W3, const float* __restrict__ b3,
    const float* __restrict__ Tp, const float* __restrict__ edes_p,
    float4* __restrict__ out, int n)
{
    __shared__ __align__(16) __bf16 lds[4 * 2048];  // per wave: h1[16][64], g2[16][64]
    const int tid = threadIdx.x;
    const int w = tid >> 6, l = tid & 63;
    const int lo = l & 15, hi = l >> 4;
    __bf16* h1buf = lds + w * 2048;
    __bf16* g2buf = h1buf + 1024;

    const int base = blockIdx.x * 64 + w * 16;
    int e = base + lo;
    if (e >= n) e = n - 1;
    const float4 xv = x[e];                 // every lane holds x of row m = lo
    const float q1 = xv.x, q2 = xv.y, p1 = xv.z, p2 = xv.w;
    const float E_des = edes_p[0];
    const float Tabs = fabsf(Tp[0]);

    // ---- layer-1 directly in A-fragment layout: lane holds (m=lo, k=8*hi+t+32*kh) ----
    bf16x8 a1[2];
#pragma unroll
    for (int kh = 0; kh < 2; kh++) {
        const int k0 = 32 * kh + 8 * hi;
        float wa[8], wb[8], bb[8];
        *(float4*)&wa[0] = *(const float4*)(W1 + k0);
        *(float4*)&wa[4] = *(const float4*)(W1 + k0 + 4);
        *(float4*)&wb[0] = *(const float4*)(W1 + HID + k0);
        *(float4*)&wb[4] = *(const float4*)(W1 + HID + k0 + 4);
        *(float4*)&bb[0] = *(const float4*)(b1 + k0);
        *(float4*)&bb[4] = *(const float4*)(b1 + k0 + 4);
#pragma unroll
        for (int t = 0; t < 8; t++) {
            float h = fast_tanh(fmaf(q1, wa[t], fmaf(q2, wb[t], bb[t])));
            a1[kh][t] = (__bf16)h;
        }
        // cache h1 (bf16) in LDS, XOR-swizzled rows (row stride 128B)
        const int idx = (lo * HID + k0) ^ ((lo & 7) << 3);
        *(bf16x8*)(h1buf + idx) = a1[kh];
    }

    // ---- GEMM1: Z2 = H1 @ W2 + b2  (B[k][n] = W2[k][n] = W2Tbf[n][k], contiguous k) ----
    f32x4 accF[4];
#pragma unroll
    for (int nt = 0; nt < 4; nt++) {
        const float b2c = b2[16 * nt + lo];
        accF[nt] = (f32x4){b2c, b2c, b2c, b2c};
    }
#pragma unroll
    for (int nt = 0; nt < 4; nt++) {
#pragma unroll
        for (int kh = 0; kh < 2; kh++) {
            const bf16x8 bfr = *(const bf16x8*)(W2Tbf + (16 * nt + lo) * HID + 32 * kh + 8 * hi);
            accF[nt] = __builtin_amdgcn_mfma_f32_16x16x32_bf16(a1[kh], bfr, accF[nt], 0, 0, 0);
        }
    }

    // ---- h2 = tanh(z2); V partials; g2 = W3*(1-h2^2) -> LDS (C-layout scatter) ----
    float vpart[4] = {0.f, 0.f, 0.f, 0.f};
#pragma unroll
    for (int nt = 0; nt < 4; nt++) {
        const int col = 16 * nt + lo;
        const float w3c = W3[col];
#pragma unroll
        for (int r = 0; r < 4; r++) {
            const float h2 = fast_tanh(accF[nt][r]);
            vpart[r] = fmaf(h2, w3c, vpart[r]);
            const float g = w3c * (1.0f - h2 * h2);
            const int row = 4 * hi + r;
            g2buf[(row * HID + col) ^ ((row & 7) << 3)] = (__bf16)g;
        }
    }

    // ---- GEMM2: R = G2 @ W2^T  (A from LDS re-layout; B[k][n] = W2[n][k], contiguous k) ----
    bf16x8 a2[2];
#pragma unroll
    for (int kh = 0; kh < 2; kh++) {
        const int idx = (lo * HID + 32 * kh + 8 * hi) ^ ((lo & 7) << 3);
        a2[kh] = *(const bf16x8*)(g2buf + idx);
    }
    f32x4 accB[4];
#pragma unroll
    for (int nt = 0; nt < 4; nt++) accB[nt] = (f32x4){0.f, 0.f, 0.f, 0.f};
#pragma unroll
    for (int nt = 0; nt < 4; nt++) {
#pragma unroll
        for (int kh = 0; kh < 2; kh++) {
            const bf16x8 bfr = *(const bf16x8*)(W2bf + (16 * nt + lo) * HID + 32 * kh + 8 * hi);
            accB[nt] = __builtin_amdgcn_mfma_f32_16x16x32_bf16(a2[kh], bfr, accB[nt], 0, 0, 0);
        }
    }

    // ---- gi = (1-h1^2)*R ; dVdq partials (per lane: 4 rows x 4 cols) ----
    float d1part[4] = {0.f, 0.f, 0.f, 0.f}, d2part[4] = {0.f, 0.f, 0.f, 0.f};
#pragma unroll
    for (int nt = 0; nt < 4; nt++) {
        const int col = 16 * nt + lo;
        const float w1a = W1[col], w1b = W1[HID + col];
#pragma unroll
        for (int r = 0; r < 4; r++) {
            const int row = 4 * hi + r;
            const float h1v = (float)h1buf[(row * HID + col) ^ ((row & 7) << 3)];
            const float gi = (1.0f - h1v * h1v) * accB[nt][r];
            d1part[r] = fmaf(w1a, gi, d1part[r]);
            d2part[r] = fmaf(w1b, gi, d2part[r]);
        }
    }

    // ---- reduce over the 16-lane col dimension (xor 1,2,4,8 stays in-group) ----
#pragma unroll
    for (int r = 0; r < 4; r++) {
#pragma unroll
        for (int off = 1; off < 16; off <<= 1) {
            vpart[r]  += __shfl_xor(vpart[r],  off, 64);
            d1part[r] += __shfl_xor(d1part[r], off, 64);
            d2part[r] += __shfl_xor(d2part[r], off, 64);
        }
    }

    // ---- gather results for this lane's row m = lo (rows live in group hi = lo>>2) ----
    const int src = (lo >> 2) << 4;
    float tV[4], t1[4], t2[4];
#pragma unroll
    for (int r = 0; r < 4; r++) {
        tV[r] = __shfl(vpart[r],  src, 64);
        t1[r] = __shfl(d1part[r], src, 64);
        t2[r] = __shfl(d2part[r], src, 64);
    }
    const int rr = lo & 3;
    float V    = (rr == 0) ? tV[0] : (rr == 1) ? tV[1] : (rr == 2) ? tV[2] : tV[3];
    float dVq1 = (rr == 0) ? t1[0] : (rr == 1) ? t1[1] : (rr == 2) ? t1[2] : t1[3];
    float dVq2 = (rr == 0) ? t2[0] : (rr == 1) ? t2[1] : (rr == 2) ? t2[2] : t2[3];
    V += b3[0];

    // ---- physics (L1=L2=M1=M2=1, G=9.81, K1=0.5, A_E=1, B_DAMP=0) ----
    float s2q, c2q, s1q, c1q;
    __sincosf(q2, &s2q, &c2q);
    __sincosf(q1, &s1q, &c1q);
    float s12 = s1q * c2q + c1q * s2q;
    float c12 = c1q * c2q - s1q * s2q;

    float c = c2q, s = s2q;
    float DEN = 2.0f - c * c;            // == 1 + s^2
    float rDEN = __builtin_amdgcn_rcpf(DEN);
    float cp1 = c + 1.0f;

    float quad = (p1 * p1 - 2.0f * cp1 * p1 * p2 + (2.0f * c + 3.0f) * p2 * p2) * rDEN;
    float kin = 0.5f * quad;
    float dqa = 1.57079632679489662f - q2;
    float pot = -9.81f * (c12 + 2.0f * c1q) + 0.5f * dqa * dqa;
    float E = pot + kin + V;

    float fac = (quad > 0.0f) ? __builtin_amdgcn_rsqf(quad) : 1.0f;
    float coef = E_des - E;
    float u1 = -dVq1 + coef * p1 * fac;
    float u2 = -dVq2 + coef * p2 * fac;

    float dq1dt = (p1 - cp1 * p2) * rDEN;
    float dq2dt = ((2.0f * c + 3.0f) * p2 - cp1 * p1) * rDEN;
    float dp1dt = -9.81f * (s12 + 2.0f * s1q) + u1;

    float inner = -p2 * p2 * s * cp1 * (c + 2.0f)
                + p1 * p2 * s * (fmaf(c, c, fmaf(2.0f, c, 2.0f)))
                - c * p1 * p1 * s
                + DEN * DEN * (fmaf(9.81f, s12, -0.5f * (3.14159265358979324f - 2.0f * q2)));
    float dp2dt = -(inner * rDEN * rDEN) + u2;

    if (l < 16 && base + lo < n) {
        float4 o;
        o.x = Tabs * dq1dt;
        o.y = Tabs * dq2dt;
        o.z = Tabs * dp1dt;
        o.w = Tabs * dp2dt;
        out[base + lo] = o;
    }
}

extern "C" void kernel_launch(void* const* d_in, const int* in_sizes, int n_in,
                              void* d_out, int out_size, void* d_ws, size_t ws_size,
                              hipStream_t stream) {
    const float* x  = (const float*)d_in[0];
    // d_in[1] = t (unused)
    const float* W1 = (const float*)d_in[2];
    const float* b1 = (const float*)d_in[3];
    const float* W2 = (const float*)d_in[4];
    const float* b2 = (const float*)d_in[5];
    const float* W3 = (const float*)d_in[6];
    const float* b3 = (const float*)d_in[7];
    const float* Tp = (const float*)d_in[8];
    const float* x0 = (const float*)d_in[9];

    float* ws = (float*)d_ws;
    float* edes = ws;                                   // 1 float (+ padding to 64B)
    __bf16* W2bf  = (__bf16*)(ws + 16);                 // 4096 bf16 = 8 KB
    __bf16* W2Tbf = W2bf + HID * HID;                   // 4096 bf16 = 8 KB

    prep_kernel<<<1, 256, 0, stream>>>(W1, b1, W2, b2, W3, b3, x0, edes, W2bf, W2Tbf);

    int n = in_sizes[0] / 4;  // 500000
    int blocks = (n + 63) / 64;  // 64 elements per 256-thread block (16 per wave)
    pend_kernel<<<blocks, 256, 0, stream>>>((const float4*)x, W1, b1, W2bf, W2Tbf,
                                            b2, W3, b3, Tp, edes, (float4*)d_out, n);
}